// Round 6
// baseline (276.712 us; speedup 1.0000x reference)
//
#include <hip/hip_runtime.h>
#include <hip/hip_fp16.h>
#include <math.h>

// FSQuantizer v6: fully-sequential heavy streams.
// z (32,512,4096) f32 -> zhat f32 + commit_loss + perplexity.
// kA: 256 blocks x 1024 thr; block reads contiguous 1MiB (b, 64-c slab, all t),
//     emits h/g c-split partials + z2/zb stats.
// kB: 512 blocks; combine 8 partials/row -> h,g f32 + BN block stats.
// kS: 1 block; BN consts + Gram + zero counts.
// kQ: 512 blocks; f64 quantize, u16 codes, histogram, commit partials.
// kW: 512 blocks; decode codes -> LDS f16 table; sequential 512KiB zhat slab
//     writes. Block 0 also finalizes commit+perplexity (kD folded).

namespace {
constexpr int Cv = 512, Tv = 4096, Bv = 32;
constexpr int Nv = Bv * Tv;                       // 131072 rows
constexpr long long TOTv = (long long)Nv * Cv;    // 67108864
constexpr int CSA = 8;                            // kA c-splits (64 c each)
constexpr int NBA = Bv * CSA;                     // 256 kA blocks

// workspace layout (bytes), 256-aligned chunks
constexpr size_t OFF_HP = 0;                                     // h_part [b][cs][t][e] f32 16MiB
constexpr size_t OFF_GP = OFF_HP + (size_t)NBA * Tv * 16;        // g_part 16MiB
constexpr size_t OFF_H  = OFF_GP + (size_t)NBA * Tv * 16;        // h_ws [n][4] f32 2MiB
constexpr size_t OFF_G  = OFF_H  + (size_t)Nv * 16;              // g_ws 2MiB
constexpr size_t OFF_B1 = OFF_G  + (size_t)Nv * 16;              // bs1 [256][2] f64
constexpr size_t OFF_B2 = OFF_B1 + 256 * 2 * 8;                  // bs2 [512][8] f64
constexpr size_t OFF_CN = OFF_B2 + 512 * 8 * 8;                  // consts [32] f64
constexpr size_t OFF_CP = OFF_CN + 32 * 8;                       // cp [512] f64
constexpr size_t OFF_CT = OFF_CP + 512 * 8;                      // counts [1024] u32
constexpr size_t OFF_CD = OFF_CT + 4096;                         // codes [Nv] u16 256KiB
}

// ---- kA: contiguous z read, h/g partials + z stats ----
__global__ __launch_bounds__(1024, 4) void fsq_kA(
    const float* __restrict__ z, const float* __restrict__ W_in,
    const float* __restrict__ W_out, const float* __restrict__ b_out,
    float* __restrict__ h_part, float* __restrict__ g_part, double* __restrict__ bs1)
{
    __shared__ float s_wi[64][4];
    __shared__ float s_wo[64][4];
    __shared__ float s_bo[64];
    __shared__ double red[2][1024];

    const int tid = threadIdx.x;
    const int bid = blockIdx.x;        // 0..255  = b*8 + cs
    const int b = bid >> 3;
    const int cs = bid & 7;
    const int c0 = cs << 6;            // 64 c per block

    if (tid < 64) {
        const int c = c0 + tid;
        *(float4*)&s_wi[tid][0] = *(const float4*)(W_in + c * 4);
        s_wo[tid][0] = W_out[c];
        s_wo[tid][1] = W_out[512 + c];
        s_wo[tid][2] = W_out[1024 + c];
        s_wo[tid][3] = W_out[1536 + c];
        s_bo[tid] = b_out[c];
    }
    __syncthreads();

    // thread owns t = tid*4..+3; block sweeps 64 sequential 16KB c-rows
    float h[4][4] = {}, g[4][4] = {};
    float z2 = 0.f, zb = 0.f;
    const float* zp = z + ((size_t)b * Cv + c0) * Tv + tid * 4;
#pragma unroll 4
    for (int c = 0; c < 64; ++c) {
        const float4 zv = *(const float4*)(zp + (size_t)c * Tv);
        const float4 wi = *(const float4*)&s_wi[c][0];   // wave-uniform broadcast
        const float4 wo = *(const float4*)&s_wo[c][0];
        const float bo = s_bo[c];
        const float zr[4] = {zv.x, zv.y, zv.z, zv.w};
#pragma unroll
        for (int j = 0; j < 4; ++j) {
            h[j][0] = fmaf(zr[j], wi.x, h[j][0]);
            h[j][1] = fmaf(zr[j], wi.y, h[j][1]);
            h[j][2] = fmaf(zr[j], wi.z, h[j][2]);
            h[j][3] = fmaf(zr[j], wi.w, h[j][3]);
            g[j][0] = fmaf(zr[j], wo.x, g[j][0]);
            g[j][1] = fmaf(zr[j], wo.y, g[j][1]);
            g[j][2] = fmaf(zr[j], wo.z, g[j][2]);
            g[j][3] = fmaf(zr[j], wo.w, g[j][3]);
            z2 = fmaf(zr[j], zr[j], z2);
        }
        zb = fmaf((zr[0] + zr[1]) + (zr[2] + zr[3]), bo, zb);
    }

    // partials: [bid][t][e] f32, thread writes 64B contiguous
    float* hp = h_part + ((size_t)bid * Tv + tid * 4) * 4;
    float* gp = g_part + ((size_t)bid * Tv + tid * 4) * 4;
#pragma unroll
    for (int j = 0; j < 4; ++j) {
        *(float4*)(hp + j * 4) = make_float4(h[j][0], h[j][1], h[j][2], h[j][3]);
        *(float4*)(gp + j * 4) = make_float4(g[j][0], g[j][1], g[j][2], g[j][3]);
    }

    red[0][tid] = (double)z2;
    red[1][tid] = (double)zb;
    __syncthreads();
    for (int s = 512; s > 0; s >>= 1) {
        if (tid < s) { red[0][tid] += red[0][tid + s]; red[1][tid] += red[1][tid + s]; }
        __syncthreads();
    }
    if (tid == 0) { bs1[bid * 2] = red[0][0]; bs1[bid * 2 + 1] = red[1][0]; }
}

// ---- kB: combine c-split partials -> h,g + BN block stats ----
__global__ __launch_bounds__(256) void fsq_kB(
    const float* __restrict__ h_part, const float* __restrict__ g_part,
    const float* __restrict__ b_in,
    float* __restrict__ h_ws, float* __restrict__ g_ws, double* __restrict__ bs2)
{
    __shared__ double red[8][256];
    const int tid = threadIdx.x;
    const int bid = blockIdx.x;        // 0..511
    const int b = bid >> 4;
    const int t = ((bid & 15) << 8) + tid;
    const int n = (b << 12) + t;

    double hd[4];
    hd[0] = (double)b_in[0]; hd[1] = (double)b_in[1];
    hd[2] = (double)b_in[2]; hd[3] = (double)b_in[3];
    float gg[4] = {0.f, 0.f, 0.f, 0.f};
#pragma unroll
    for (int cs = 0; cs < 8; ++cs) {
        const size_t base = ((size_t)(b * 8 + cs) * Tv + t) * 4;
        const float4 p = *(const float4*)(h_part + base);
        const float4 q = *(const float4*)(g_part + base);
        hd[0] += (double)p.x; hd[1] += (double)p.y;
        hd[2] += (double)p.z; hd[3] += (double)p.w;
        gg[0] += q.x; gg[1] += q.y; gg[2] += q.z; gg[3] += q.w;
    }

    *(float4*)(h_ws + (size_t)n * 4) =
        make_float4((float)hd[0], (float)hd[1], (float)hd[2], (float)hd[3]);
    *(float4*)(g_ws + (size_t)n * 4) = make_float4(gg[0], gg[1], gg[2], gg[3]);

#pragma unroll
    for (int e = 0; e < 4; ++e) {
        red[e][tid] = hd[e];
        red[4 + e][tid] = hd[e] * hd[e];
    }
    __syncthreads();
    for (int s = 128; s > 0; s >>= 1) {
        if (tid < s) {
#pragma unroll
            for (int k = 0; k < 8; ++k) red[k][tid] += red[k][tid + s];
        }
        __syncthreads();
    }
    if (tid == 0) {
#pragma unroll
        for (int k = 0; k < 8; ++k) bs2[bid * 8 + k] = red[k][0];
    }
}

// ---- kS: BN consts + Gram + zero counts ----
__global__ __launch_bounds__(256) void fsq_kS(
    const float* __restrict__ gamma, const float* __restrict__ beta,
    const float* __restrict__ W_out, const float* __restrict__ b_out,
    const double* __restrict__ bs1, const double* __restrict__ bs2,
    double* __restrict__ consts, unsigned* __restrict__ counts)
{
    __shared__ double sbuf[15][256];
    const int tid = threadIdx.x;

    for (int i = tid; i < 1000; i += 256) counts[i] = 0;

    double a[10] = {};
    for (int r = tid; r < 512; r += 256) {
        const double* p = bs2 + (size_t)r * 8;
#pragma unroll
        for (int k = 0; k < 8; ++k) a[k] += p[k];
    }
    a[8] = bs1[tid * 2];          // 256 entries exactly
    a[9] = bs1[tid * 2 + 1];
#pragma unroll
    for (int k = 0; k < 10; ++k) sbuf[k][tid] = a[k];
    __syncthreads();
    for (int s = 128; s > 0; s >>= 1) {
        if (tid < s) {
#pragma unroll
            for (int k = 0; k < 10; ++k) sbuf[k][tid] += sbuf[k][tid + s];
        }
        __syncthreads();
    }
    double tot[10];
    if (tid == 0) {
#pragma unroll
        for (int k = 0; k < 10; ++k) tot[k] = sbuf[k][0];
    }
    __syncthreads();

    double gr[15] = {};
    for (int c = tid; c < 512; c += 256) {
        const double w0 = (double)W_out[c], w1 = (double)W_out[512 + c];
        const double w2 = (double)W_out[1024 + c], w3 = (double)W_out[1536 + c];
        const double bb = (double)b_out[c];
        gr[0] += w0 * w0; gr[1] += w0 * w1; gr[2] += w0 * w2; gr[3] += w0 * w3;
        gr[4] += w1 * w1; gr[5] += w1 * w2; gr[6] += w1 * w3;
        gr[7] += w2 * w2; gr[8] += w2 * w3; gr[9] += w3 * w3;
        gr[10] += w0 * bb; gr[11] += w1 * bb; gr[12] += w2 * bb; gr[13] += w3 * bb;
        gr[14] += bb * bb;
    }
#pragma unroll
    for (int k = 0; k < 15; ++k) sbuf[k][tid] = gr[k];
    __syncthreads();
    for (int s = 128; s > 0; s >>= 1) {
        if (tid < s) {
#pragma unroll
            for (int k = 0; k < 15; ++k) sbuf[k][tid] += sbuf[k][tid + s];
        }
        __syncthreads();
    }
    if (tid == 0) {
        const double Ninv = 1.0 / (double)Nv;
#pragma unroll
        for (int e = 0; e < 4; ++e) {
            const double mu = tot[e] * Ninv;
            const double var = tot[4 + e] * Ninv - mu * mu;   // biased, matches jnp.var
            const double sc = (double)gamma[e] / sqrt(var + 1e-5);
            consts[e] = sc;
            consts[4 + e] = (double)beta[e] - mu * sc;
        }
        consts[8] = tot[8];   // sum z^2
        consts[9] = tot[9];   // sum z.b_out
#pragma unroll
        for (int k = 0; k < 15; ++k) consts[16 + k] = sbuf[k][0];
        constexpr double hl0 = (8.0 - 1.0) * (1.0 - 1e-3) / 2.0;
        consts[31] = tan(0.5 / hl0);
    }
}

// ---- kQ: quantize rows -> codes + histogram + commit partials ----
__global__ __launch_bounds__(256) void fsq_kQ(
    const float* __restrict__ h_ws, const float* __restrict__ g_ws,
    const double* __restrict__ consts, unsigned* __restrict__ counts,
    unsigned short* __restrict__ codes, double* __restrict__ cp)
{
    __shared__ double s_cp[4];
    const int tid = threadIdx.x;
    const int lane = tid & 63;
    const int w = tid >> 6;
    const int n = blockIdx.x * 256 + tid;

    const double sc0 = consts[0], sc1 = consts[1], sc2 = consts[2], sc3 = consts[3];
    const double bi0 = consts[4], bi1 = consts[5], bi2 = consts[6], bi3 = consts[7];
    const double shift0 = consts[31];
    constexpr double hl0 = (8.0 - 1.0) * (1.0 - 1e-3) / 2.0;   // 3.4965
    constexpr double hl1 = (5.0 - 1.0) * (1.0 - 1e-3) / 2.0;   // 1.998

    const float4 hv = *(const float4*)(h_ws + (size_t)n * 4);
    const double hn0 = fma((double)hv.x, sc0, bi0);
    const double hn1 = fma((double)hv.y, sc1, bi1);
    const double hn2 = fma((double)hv.z, sc2, bi2);
    const double hn3 = fma((double)hv.w, sc3, bi3);
    const double r0 = rint(tanh(hn0 + shift0) * hl0 - 0.5);    // [-4,3]
    const double r1 = rint(tanh(hn1) * hl1);                   // [-2,2]
    const double r2 = rint(tanh(hn2) * hl1);
    const double r3 = rint(tanh(hn3) * hl1);
    const double zd0 = r0 * 0.25, zd1 = r1 * 0.5, zd2 = r2 * 0.5, zd3 = r3 * 0.5;

    const int code = ((int)r0 + 4) + ((int)r1 + 2) * 8 + ((int)r2 + 2) * 40
                   + ((int)r3 + 2) * 200;
    codes[n] = (unsigned short)code;
    atomicAdd(&counts[code], 1u);

    const float4 gv = *(const float4*)(g_ws + (size_t)n * 4);
    const double cg = zd0 * (double)gv.x + zd1 * (double)gv.y
                    + zd2 * (double)gv.z + zd3 * (double)gv.w;
    double q = consts[16 + 14]
             + 2.0 * (zd0 * consts[16 + 10] + zd1 * consts[16 + 11]
                    + zd2 * consts[16 + 12] + zd3 * consts[16 + 13])
             + zd0 * zd0 * consts[16 + 0] + zd1 * zd1 * consts[16 + 4]
             + zd2 * zd2 * consts[16 + 7] + zd3 * zd3 * consts[16 + 9]
             + 2.0 * (zd0 * zd1 * consts[16 + 1] + zd0 * zd2 * consts[16 + 2]
                    + zd0 * zd3 * consts[16 + 3] + zd1 * zd2 * consts[16 + 5]
                    + zd1 * zd3 * consts[16 + 6] + zd2 * zd3 * consts[16 + 8]);
    double qsum = q - 2.0 * cg;
#pragma unroll
    for (int m = 1; m < 64; m <<= 1) qsum += __shfl_xor(qsum, m, 64);
    if (lane == 0) s_cp[w] = qsum;
    __syncthreads();
    if (tid == 0) cp[blockIdx.x] = (s_cp[0] + s_cp[1]) + (s_cp[2] + s_cp[3]);
}

// ---- kW: decode codes -> LDS f16 table; sequential zhat slab writes (+finalize) ----
__global__ __launch_bounds__(256, 4) void fsq_kW(
    const unsigned short* __restrict__ codes, const float* __restrict__ W_out,
    const float* __restrict__ b_out, const double* __restrict__ cp,
    const double* __restrict__ consts, const unsigned* __restrict__ counts,
    float* __restrict__ out, int out_size)
{
    __shared__ __half2 s_zn[4096][2];   // 32 KiB, f16 exact for quarter-steps
    __shared__ float s_wo[32][4];
    __shared__ float s_bo[32];
    __shared__ double r1[256], r2[256];

    const int tid = threadIdx.x;
    const int bid = blockIdx.x;        // 0..511
    const int b = bid >> 4;
    const int c0 = (bid & 15) << 5;    // 32 c per block

    if (bid == 0) {                    // folded kD: finalize scalars
        double c_ = cp[tid] + cp[tid + 256];
        double pl = 0.0;
        for (int i = tid; i < 1000; i += 256) {
            const double em = (double)counts[i] / (double)Nv;
            pl += em * log(em + 1e-10);
        }
        r1[tid] = c_; r2[tid] = pl;
        __syncthreads();
        for (int s = 128; s > 0; s >>= 1) {
            if (tid < s) { r1[tid] += r1[tid + s]; r2[tid] += r2[tid + s]; }
            __syncthreads();
        }
        if (tid == 0) {
            out[out_size - 2] = (float)((consts[8] - 2.0 * consts[9] + r1[0]) / (double)TOTv);
            out[out_size - 1] = (float)exp(-r2[0]);
        }
        __syncthreads();
    }

    if (tid < 32) {
        const int c = c0 + tid;
        s_wo[tid][0] = W_out[c];
        s_wo[tid][1] = W_out[512 + c];
        s_wo[tid][2] = W_out[1024 + c];
        s_wo[tid][3] = W_out[1536 + c];
        s_bo[tid] = b_out[c];
    }
    // decode this b's 4096 codes
    for (int r = tid; r < 4096; r += 256) {
        const int code = (int)codes[(b << 12) + r];
        const int x0 = code & 7;
        const int c1 = code >> 3;
        const int x1 = c1 % 5;
        const int c2 = c1 / 5;
        const int x2 = c2 % 5;
        const int x3 = c2 / 5;
        const float zn0 = (float)(x0 - 4) * 0.25f;
        const float zn1 = (float)(x1 - 2) * 0.5f;
        const float zn2 = (float)(x2 - 2) * 0.5f;
        const float zn3 = (float)(x3 - 2) * 0.5f;
        s_zn[r][0] = __floats2half2_rn(zn0, zn1);
        s_zn[r][1] = __floats2half2_rn(zn2, zn3);
    }
    __syncthreads();

    // wave w writes c-rows c0 + w*8 .. +7, each as 16 sequential 1KiB wave-stores
    const int w = tid >> 6;
    const int lane = tid & 63;
#pragma unroll
    for (int cc = 0; cc < 8; ++cc) {
        const int ci = w * 8 + cc;
        const float4 wo = *(const float4*)&s_wo[ci][0];
        const float bo = s_bo[ci];
        float* op = out + ((size_t)b * Cv + (c0 + ci)) * Tv;
        for (int it = 0; it < 16; ++it) {
            const int t = it * 256 + lane * 4;
            float4 o;
#pragma unroll
            for (int j = 0; j < 4; ++j) {
                const float2 p01 = __half22float2(s_zn[t + j][0]);
                const float2 p23 = __half22float2(s_zn[t + j][1]);
                (&o.x)[j] = fmaf(p01.x, wo.x, fmaf(p01.y, wo.y,
                            fmaf(p23.x, wo.z, fmaf(p23.y, wo.w, bo))));
            }
            *(float4*)(op + t) = o;
        }
    }
}

extern "C" void kernel_launch(void* const* d_in, const int* in_sizes, int n_in,
                              void* d_out, int out_size, void* d_ws, size_t ws_size,
                              hipStream_t stream) {
    const float* z     = (const float*)d_in[0];
    const float* W_in  = (const float*)d_in[1];
    const float* b_in  = (const float*)d_in[2];
    const float* gamma = (const float*)d_in[3];
    const float* beta  = (const float*)d_in[4];
    const float* W_out = (const float*)d_in[5];
    const float* b_out = (const float*)d_in[6];
    float* out = (float*)d_out;

    char* ws = (char*)d_ws;
    float*          h_part = (float*)(ws + OFF_HP);
    float*          g_part = (float*)(ws + OFF_GP);
    float*          h_ws   = (float*)(ws + OFF_H);
    float*          g_ws   = (float*)(ws + OFF_G);
    double*         bs1    = (double*)(ws + OFF_B1);
    double*         bs2    = (double*)(ws + OFF_B2);
    double*         consts = (double*)(ws + OFF_CN);
    double*         cp     = (double*)(ws + OFF_CP);
    unsigned*       counts = (unsigned*)(ws + OFF_CT);
    unsigned short* codes  = (unsigned short*)(ws + OFF_CD);

    fsq_kA<<<NBA, 1024, 0, stream>>>(z, W_in, W_out, b_out, h_part, g_part, bs1);
    fsq_kB<<<512, 256, 0, stream>>>(h_part, g_part, b_in, h_ws, g_ws, bs2);
    fsq_kS<<<1, 256, 0, stream>>>(gamma, beta, W_out, b_out, bs1, bs2, consts, counts);
    fsq_kQ<<<512, 256, 0, stream>>>(h_ws, g_ws, consts, counts, codes, cp);
    fsq_kW<<<512, 256, 0, stream>>>(codes, W_out, b_out, cp, consts, counts, out, out_size);
}

// Round 7
// 191.821 us; speedup vs baseline: 1.4425x; 1.4425x over previous
//
#include <hip/hip_runtime.h>
#include <math.h>

// FSQuantizer v7: v6 with conflict-free kW (4 float planes, 4B/lane stores).
// z (32,512,4096) f32 -> zhat f32 + commit_loss + perplexity.
// kA: 256 blocks x 1024 thr; block reads contiguous 1MiB (b, 64-c slab, all t),
//     emits h/g c-split partials + z2/zb stats.
// kB: 512 blocks; combine 8 partials/row -> h,g f32 + BN block stats.
// kS: 1 block; BN consts + Gram + zero counts.
// kQ: 512 blocks; f64 quantize, u16 codes, histogram, commit partials.
// kW: 512 blocks; decode codes -> 4 conflict-free LDS float planes; sequential
//     512KiB zhat slab writes (4B/lane). Block 0 finalizes commit+perplexity.

namespace {
constexpr int Cv = 512, Tv = 4096, Bv = 32;
constexpr int Nv = Bv * Tv;                       // 131072 rows
constexpr long long TOTv = (long long)Nv * Cv;    // 67108864
constexpr int CSA = 8;                            // kA c-splits (64 c each)
constexpr int NBA = Bv * CSA;                     // 256 kA blocks

// workspace layout (bytes)
constexpr size_t OFF_HP = 0;                                     // h_part [b][cs][t][e] f32 16MiB
constexpr size_t OFF_GP = OFF_HP + (size_t)NBA * Tv * 16;        // g_part 16MiB
constexpr size_t OFF_H  = OFF_GP + (size_t)NBA * Tv * 16;        // h_ws [n][4] f32 2MiB
constexpr size_t OFF_G  = OFF_H  + (size_t)Nv * 16;              // g_ws 2MiB
constexpr size_t OFF_B1 = OFF_G  + (size_t)Nv * 16;              // bs1 [256][2] f64
constexpr size_t OFF_B2 = OFF_B1 + 256 * 2 * 8;                  // bs2 [512][8] f64
constexpr size_t OFF_CN = OFF_B2 + 512 * 8 * 8;                  // consts [32] f64
constexpr size_t OFF_CP = OFF_CN + 32 * 8;                       // cp [512] f64
constexpr size_t OFF_CT = OFF_CP + 512 * 8;                      // counts [1024] u32
constexpr size_t OFF_CD = OFF_CT + 4096;                         // codes [Nv] u16 256KiB
}

// ---- kA: contiguous z read, h/g partials + z stats ----
__global__ __launch_bounds__(1024, 4) void fsq_kA(
    const float* __restrict__ z, const float* __restrict__ W_in,
    const float* __restrict__ W_out, const float* __restrict__ b_out,
    float* __restrict__ h_part, float* __restrict__ g_part, double* __restrict__ bs1)
{
    __shared__ float s_wi[64][4];
    __shared__ float s_wo[64][4];
    __shared__ float s_bo[64];
    __shared__ double red[2][1024];

    const int tid = threadIdx.x;
    const int bid = blockIdx.x;        // 0..255  = b*8 + cs
    const int b = bid >> 3;
    const int cs = bid & 7;
    const int c0 = cs << 6;            // 64 c per block

    if (tid < 64) {
        const int c = c0 + tid;
        *(float4*)&s_wi[tid][0] = *(const float4*)(W_in + c * 4);
        s_wo[tid][0] = W_out[c];
        s_wo[tid][1] = W_out[512 + c];
        s_wo[tid][2] = W_out[1024 + c];
        s_wo[tid][3] = W_out[1536 + c];
        s_bo[tid] = b_out[c];
    }
    __syncthreads();

    // thread owns t = tid*4..+3; block sweeps 64 sequential 16KB c-rows
    float h[4][4] = {}, g[4][4] = {};
    float z2 = 0.f, zb = 0.f;
    const float* zp = z + ((size_t)b * Cv + c0) * Tv + tid * 4;
#pragma unroll 4
    for (int c = 0; c < 64; ++c) {
        const float4 zv = *(const float4*)(zp + (size_t)c * Tv);
        const float4 wi = *(const float4*)&s_wi[c][0];   // wave-uniform broadcast
        const float4 wo = *(const float4*)&s_wo[c][0];
        const float bo = s_bo[c];
        const float zr[4] = {zv.x, zv.y, zv.z, zv.w};
#pragma unroll
        for (int j = 0; j < 4; ++j) {
            h[j][0] = fmaf(zr[j], wi.x, h[j][0]);
            h[j][1] = fmaf(zr[j], wi.y, h[j][1]);
            h[j][2] = fmaf(zr[j], wi.z, h[j][2]);
            h[j][3] = fmaf(zr[j], wi.w, h[j][3]);
            g[j][0] = fmaf(zr[j], wo.x, g[j][0]);
            g[j][1] = fmaf(zr[j], wo.y, g[j][1]);
            g[j][2] = fmaf(zr[j], wo.z, g[j][2]);
            g[j][3] = fmaf(zr[j], wo.w, g[j][3]);
            z2 = fmaf(zr[j], zr[j], z2);
        }
        zb = fmaf((zr[0] + zr[1]) + (zr[2] + zr[3]), bo, zb);
    }

    // partials: [bid][t][e] f32, thread writes 64B contiguous
    float* hp = h_part + ((size_t)bid * Tv + tid * 4) * 4;
    float* gp = g_part + ((size_t)bid * Tv + tid * 4) * 4;
#pragma unroll
    for (int j = 0; j < 4; ++j) {
        *(float4*)(hp + j * 4) = make_float4(h[j][0], h[j][1], h[j][2], h[j][3]);
        *(float4*)(gp + j * 4) = make_float4(g[j][0], g[j][1], g[j][2], g[j][3]);
    }

    red[0][tid] = (double)z2;
    red[1][tid] = (double)zb;
    __syncthreads();
    for (int s = 512; s > 0; s >>= 1) {
        if (tid < s) { red[0][tid] += red[0][tid + s]; red[1][tid] += red[1][tid + s]; }
        __syncthreads();
    }
    if (tid == 0) { bs1[bid * 2] = red[0][0]; bs1[bid * 2 + 1] = red[1][0]; }
}

// ---- kB: combine c-split partials -> h,g + BN block stats ----
__global__ __launch_bounds__(256) void fsq_kB(
    const float* __restrict__ h_part, const float* __restrict__ g_part,
    const float* __restrict__ b_in,
    float* __restrict__ h_ws, float* __restrict__ g_ws, double* __restrict__ bs2)
{
    __shared__ double red[8][256];
    const int tid = threadIdx.x;
    const int bid = blockIdx.x;        // 0..511
    const int b = bid >> 4;
    const int t = ((bid & 15) << 8) + tid;
    const int n = (b << 12) + t;

    double hd[4];
    hd[0] = (double)b_in[0]; hd[1] = (double)b_in[1];
    hd[2] = (double)b_in[2]; hd[3] = (double)b_in[3];
    float gg[4] = {0.f, 0.f, 0.f, 0.f};
#pragma unroll
    for (int cs = 0; cs < 8; ++cs) {
        const size_t base = ((size_t)(b * 8 + cs) * Tv + t) * 4;
        const float4 p = *(const float4*)(h_part + base);
        const float4 q = *(const float4*)(g_part + base);
        hd[0] += (double)p.x; hd[1] += (double)p.y;
        hd[2] += (double)p.z; hd[3] += (double)p.w;
        gg[0] += q.x; gg[1] += q.y; gg[2] += q.z; gg[3] += q.w;
    }

    *(float4*)(h_ws + (size_t)n * 4) =
        make_float4((float)hd[0], (float)hd[1], (float)hd[2], (float)hd[3]);
    *(float4*)(g_ws + (size_t)n * 4) = make_float4(gg[0], gg[1], gg[2], gg[3]);

#pragma unroll
    for (int e = 0; e < 4; ++e) {
        red[e][tid] = hd[e];
        red[4 + e][tid] = hd[e] * hd[e];
    }
    __syncthreads();
    for (int s = 128; s > 0; s >>= 1) {
        if (tid < s) {
#pragma unroll
            for (int k = 0; k < 8; ++k) red[k][tid] += red[k][tid + s];
        }
        __syncthreads();
    }
    if (tid == 0) {
#pragma unroll
        for (int k = 0; k < 8; ++k) bs2[bid * 8 + k] = red[k][0];
    }
}

// ---- kS: BN consts + Gram + zero counts ----
__global__ __launch_bounds__(256) void fsq_kS(
    const float* __restrict__ gamma, const float* __restrict__ beta,
    const float* __restrict__ W_out, const float* __restrict__ b_out,
    const double* __restrict__ bs1, const double* __restrict__ bs2,
    double* __restrict__ consts, unsigned* __restrict__ counts)
{
    __shared__ double sbuf[15][256];
    const int tid = threadIdx.x;

    for (int i = tid; i < 1000; i += 256) counts[i] = 0;

    double a[10] = {};
    for (int r = tid; r < 512; r += 256) {
        const double* p = bs2 + (size_t)r * 8;
#pragma unroll
        for (int k = 0; k < 8; ++k) a[k] += p[k];
    }
    a[8] = bs1[tid * 2];          // 256 entries exactly
    a[9] = bs1[tid * 2 + 1];
#pragma unroll
    for (int k = 0; k < 10; ++k) sbuf[k][tid] = a[k];
    __syncthreads();
    for (int s = 128; s > 0; s >>= 1) {
        if (tid < s) {
#pragma unroll
            for (int k = 0; k < 10; ++k) sbuf[k][tid] += sbuf[k][tid + s];
        }
        __syncthreads();
    }
    double tot[10];
    if (tid == 0) {
#pragma unroll
        for (int k = 0; k < 10; ++k) tot[k] = sbuf[k][0];
    }
    __syncthreads();

    double gr[15] = {};
    for (int c = tid; c < 512; c += 256) {
        const double w0 = (double)W_out[c], w1 = (double)W_out[512 + c];
        const double w2 = (double)W_out[1024 + c], w3 = (double)W_out[1536 + c];
        const double bb = (double)b_out[c];
        gr[0] += w0 * w0; gr[1] += w0 * w1; gr[2] += w0 * w2; gr[3] += w0 * w3;
        gr[4] += w1 * w1; gr[5] += w1 * w2; gr[6] += w1 * w3;
        gr[7] += w2 * w2; gr[8] += w2 * w3; gr[9] += w3 * w3;
        gr[10] += w0 * bb; gr[11] += w1 * bb; gr[12] += w2 * bb; gr[13] += w3 * bb;
        gr[14] += bb * bb;
    }
#pragma unroll
    for (int k = 0; k < 15; ++k) sbuf[k][tid] = gr[k];
    __syncthreads();
    for (int s = 128; s > 0; s >>= 1) {
        if (tid < s) {
#pragma unroll
            for (int k = 0; k < 15; ++k) sbuf[k][tid] += sbuf[k][tid + s];
        }
        __syncthreads();
    }
    if (tid == 0) {
        const double Ninv = 1.0 / (double)Nv;
#pragma unroll
        for (int e = 0; e < 4; ++e) {
            const double mu = tot[e] * Ninv;
            const double var = tot[4 + e] * Ninv - mu * mu;   // biased, matches jnp.var
            const double sc = (double)gamma[e] / sqrt(var + 1e-5);
            consts[e] = sc;
            consts[4 + e] = (double)beta[e] - mu * sc;
        }
        consts[8] = tot[8];   // sum z^2
        consts[9] = tot[9];   // sum z.b_out
#pragma unroll
        for (int k = 0; k < 15; ++k) consts[16 + k] = sbuf[k][0];
        constexpr double hl0 = (8.0 - 1.0) * (1.0 - 1e-3) / 2.0;
        consts[31] = tan(0.5 / hl0);
    }
}

// ---- kQ: quantize rows -> codes + histogram + commit partials ----
__global__ __launch_bounds__(256) void fsq_kQ(
    const float* __restrict__ h_ws, const float* __restrict__ g_ws,
    const double* __restrict__ consts, unsigned* __restrict__ counts,
    unsigned short* __restrict__ codes, double* __restrict__ cp)
{
    __shared__ double s_cp[4];
    const int tid = threadIdx.x;
    const int lane = tid & 63;
    const int w = tid >> 6;
    const int n = blockIdx.x * 256 + tid;

    const double sc0 = consts[0], sc1 = consts[1], sc2 = consts[2], sc3 = consts[3];
    const double bi0 = consts[4], bi1 = consts[5], bi2 = consts[6], bi3 = consts[7];
    const double shift0 = consts[31];
    constexpr double hl0 = (8.0 - 1.0) * (1.0 - 1e-3) / 2.0;   // 3.4965
    constexpr double hl1 = (5.0 - 1.0) * (1.0 - 1e-3) / 2.0;   // 1.998

    const float4 hv = *(const float4*)(h_ws + (size_t)n * 4);
    const double hn0 = fma((double)hv.x, sc0, bi0);
    const double hn1 = fma((double)hv.y, sc1, bi1);
    const double hn2 = fma((double)hv.z, sc2, bi2);
    const double hn3 = fma((double)hv.w, sc3, bi3);
    const double r0 = rint(tanh(hn0 + shift0) * hl0 - 0.5);    // [-4,3]
    const double r1 = rint(tanh(hn1) * hl1);                   // [-2,2]
    const double r2 = rint(tanh(hn2) * hl1);
    const double r3 = rint(tanh(hn3) * hl1);
    const double zd0 = r0 * 0.25, zd1 = r1 * 0.5, zd2 = r2 * 0.5, zd3 = r3 * 0.5;

    const int code = ((int)r0 + 4) + ((int)r1 + 2) * 8 + ((int)r2 + 2) * 40
                   + ((int)r3 + 2) * 200;
    codes[n] = (unsigned short)code;
    atomicAdd(&counts[code], 1u);

    const float4 gv = *(const float4*)(g_ws + (size_t)n * 4);
    const double cg = zd0 * (double)gv.x + zd1 * (double)gv.y
                    + zd2 * (double)gv.z + zd3 * (double)gv.w;
    double q = consts[16 + 14]
             + 2.0 * (zd0 * consts[16 + 10] + zd1 * consts[16 + 11]
                    + zd2 * consts[16 + 12] + zd3 * consts[16 + 13])
             + zd0 * zd0 * consts[16 + 0] + zd1 * zd1 * consts[16 + 4]
             + zd2 * zd2 * consts[16 + 7] + zd3 * zd3 * consts[16 + 9]
             + 2.0 * (zd0 * zd1 * consts[16 + 1] + zd0 * zd2 * consts[16 + 2]
                    + zd0 * zd3 * consts[16 + 3] + zd1 * zd2 * consts[16 + 5]
                    + zd1 * zd3 * consts[16 + 6] + zd2 * zd3 * consts[16 + 8]);
    double qsum = q - 2.0 * cg;
#pragma unroll
    for (int m = 1; m < 64; m <<= 1) qsum += __shfl_xor(qsum, m, 64);
    if (lane == 0) s_cp[w] = qsum;
    __syncthreads();
    if (tid == 0) cp[blockIdx.x] = (s_cp[0] + s_cp[1]) + (s_cp[2] + s_cp[3]);
}

// ---- kW: decode codes -> 4 conflict-free LDS planes; sequential zhat writes ----
__global__ __launch_bounds__(256, 2) void fsq_kW(
    const unsigned short* __restrict__ codes, const float* __restrict__ W_out,
    const float* __restrict__ b_out, const double* __restrict__ cp,
    const double* __restrict__ consts, const unsigned* __restrict__ counts,
    float* __restrict__ out, int out_size)
{
    __shared__ float s_p0[4096];   // 4 planes x 16 KiB = 64 KiB, conflict-free reads
    __shared__ float s_p1[4096];
    __shared__ float s_p2[4096];
    __shared__ float s_p3[4096];
    __shared__ float s_wo[32][4];
    __shared__ float s_bo[32];
    __shared__ double r1[256], r2[256];

    const int tid = threadIdx.x;
    const int bid = blockIdx.x;        // 0..511
    const int b = bid >> 4;
    const int c0 = (bid & 15) << 5;    // 32 c per block

    if (bid == 0) {                    // folded kD: finalize scalars
        double c_ = cp[tid] + cp[tid + 256];
        double pl = 0.0;
        for (int i = tid; i < 1000; i += 256) {
            const double em = (double)counts[i] / (double)Nv;
            pl += em * log(em + 1e-10);
        }
        r1[tid] = c_; r2[tid] = pl;
        __syncthreads();
        for (int s = 128; s > 0; s >>= 1) {
            if (tid < s) { r1[tid] += r1[tid + s]; r2[tid] += r2[tid + s]; }
            __syncthreads();
        }
        if (tid == 0) {
            out[out_size - 2] = (float)((consts[8] - 2.0 * consts[9] + r1[0]) / (double)TOTv);
            out[out_size - 1] = (float)exp(-r2[0]);
        }
        __syncthreads();
    }

    if (tid < 32) {
        const int c = c0 + tid;
        s_wo[tid][0] = W_out[c];
        s_wo[tid][1] = W_out[512 + c];
        s_wo[tid][2] = W_out[1024 + c];
        s_wo[tid][3] = W_out[1536 + c];
        s_bo[tid] = b_out[c];
    }
    // decode this b's 4096 codes into planes (conflict-free: stride-256 writes)
    for (int r = tid; r < 4096; r += 256) {
        const int code = (int)codes[(b << 12) + r];
        const int x0 = code & 7;
        const int c1 = code >> 3;
        const int x1 = c1 % 5;
        const int c2 = c1 / 5;
        const int x2 = c2 % 5;
        const int x3 = c2 / 5;
        s_p0[r] = (float)(x0 - 4) * 0.25f;
        s_p1[r] = (float)(x1 - 2) * 0.5f;
        s_p2[r] = (float)(x2 - 2) * 0.5f;
        s_p3[r] = (float)(x3 - 2) * 0.5f;
    }
    __syncthreads();

    // wave w writes c-rows c0 + w*8 .. +7, each row = 64 sequential 256B stores
    const int w = tid >> 6;
    const int lane = tid & 63;
#pragma unroll
    for (int cc = 0; cc < 8; ++cc) {
        const int ci = w * 8 + cc;
        const float4 wo = *(const float4*)&s_wo[ci][0];
        const float bo = s_bo[ci];
        float* op = out + ((size_t)b * Cv + (c0 + ci)) * Tv;
#pragma unroll 4
        for (int it = 0; it < 64; ++it) {
            const int t = it * 64 + lane;   // lane-contiguous: conflict-free LDS reads
            const float o = fmaf(s_p0[t], wo.x, fmaf(s_p1[t], wo.y,
                            fmaf(s_p2[t], wo.z, fmaf(s_p3[t], wo.w, bo))));
            op[t] = o;
        }
    }
}

extern "C" void kernel_launch(void* const* d_in, const int* in_sizes, int n_in,
                              void* d_out, int out_size, void* d_ws, size_t ws_size,
                              hipStream_t stream) {
    const float* z     = (const float*)d_in[0];
    const float* W_in  = (const float*)d_in[1];
    const float* b_in  = (const float*)d_in[2];
    const float* gamma = (const float*)d_in[3];
    const float* beta  = (const float*)d_in[4];
    const float* W_out = (const float*)d_in[5];
    const float* b_out = (const float*)d_in[6];
    float* out = (float*)d_out;

    char* ws = (char*)d_ws;
    float*          h_part = (float*)(ws + OFF_HP);
    float*          g_part = (float*)(ws + OFF_GP);
    float*          h_ws   = (float*)(ws + OFF_H);
    float*          g_ws   = (float*)(ws + OFF_G);
    double*         bs1    = (double*)(ws + OFF_B1);
    double*         bs2    = (double*)(ws + OFF_B2);
    double*         consts = (double*)(ws + OFF_CN);
    double*         cp     = (double*)(ws + OFF_CP);
    unsigned*       counts = (unsigned*)(ws + OFF_CT);
    unsigned short* codes  = (unsigned short*)(ws + OFF_CD);

    fsq_kA<<<NBA, 1024, 0, stream>>>(z, W_in, W_out, b_out, h_part, g_part, bs1);
    fsq_kB<<<512, 256, 0, stream>>>(h_part, g_part, b_in, h_ws, g_ws, bs2);
    fsq_kS<<<1, 256, 0, stream>>>(gamma, beta, W_out, b_out, bs1, bs2, consts, counts);
    fsq_kQ<<<512, 256, 0, stream>>>(h_ws, g_ws, consts, counts, codes, cp);
    fsq_kW<<<512, 256, 0, stream>>>(codes, W_out, b_out, cp, consts, counts, out, out_size);
}

// Round 9
// 191.388 us; speedup vs baseline: 1.4458x; 1.0023x over previous
//
#include <hip/hip_runtime.h>
#include <math.h>

// FSQuantizer v8b: v8 with native-vector nontemporal stores (compile fix).
// z (32,512,4096) f32 -> zhat f32 + commit_loss + perplexity.
// kA: 256 blocks x 1024 thr; contiguous 1MiB read per block; h/g c-split partials.
// kB: 512 blocks; combine 8 partials/row -> h,g f32 + BN block stats.
// kS: 1 block; BN consts + Gram + zero counts.
// kQ: 512 blocks; f64 quantize, u16 codes, histogram, commit partials.
// kW: 512 blocks x 1024 thr; thread holds zn[4][4] in regs for its 4 consecutive t,
//     sweeps 32 c-rows with 16KB-row-contiguous f32x4 nt-stores. Block 0 finalizes.

typedef float f32x4 __attribute__((ext_vector_type(4)));

namespace {
constexpr int Cv = 512, Tv = 4096, Bv = 32;
constexpr int Nv = Bv * Tv;                       // 131072 rows
constexpr long long TOTv = (long long)Nv * Cv;    // 67108864
constexpr int CSA = 8;                            // kA c-splits (64 c each)
constexpr int NBA = Bv * CSA;                     // 256 kA blocks

// workspace layout (bytes)
constexpr size_t OFF_HP = 0;                                     // h_part [b][cs][t][e] f32 16MiB
constexpr size_t OFF_GP = OFF_HP + (size_t)NBA * Tv * 16;        // g_part 16MiB
constexpr size_t OFF_H  = OFF_GP + (size_t)NBA * Tv * 16;        // h_ws [n][4] f32 2MiB
constexpr size_t OFF_G  = OFF_H  + (size_t)Nv * 16;              // g_ws 2MiB
constexpr size_t OFF_B1 = OFF_G  + (size_t)Nv * 16;              // bs1 [256][2] f64
constexpr size_t OFF_B2 = OFF_B1 + 256 * 2 * 8;                  // bs2 [512][8] f64
constexpr size_t OFF_CN = OFF_B2 + 512 * 8 * 8;                  // consts [32] f64
constexpr size_t OFF_CP = OFF_CN + 32 * 8;                       // cp [512] f64
constexpr size_t OFF_CT = OFF_CP + 512 * 8;                      // counts [1024] u32
constexpr size_t OFF_CD = OFF_CT + 4096;                         // codes [Nv] u16 256KiB
}

// ---- kA: contiguous z read, h/g partials + z stats ----
__global__ __launch_bounds__(1024, 4) void fsq_kA(
    const float* __restrict__ z, const float* __restrict__ W_in,
    const float* __restrict__ W_out, const float* __restrict__ b_out,
    float* __restrict__ h_part, float* __restrict__ g_part, double* __restrict__ bs1)
{
    __shared__ float s_wi[64][4];
    __shared__ float s_wo[64][4];
    __shared__ float s_bo[64];
    __shared__ double red[2][1024];

    const int tid = threadIdx.x;
    const int bid = blockIdx.x;        // 0..255  = b*8 + cs
    const int b = bid >> 3;
    const int cs = bid & 7;
    const int c0 = cs << 6;            // 64 c per block

    if (tid < 64) {
        const int c = c0 + tid;
        *(float4*)&s_wi[tid][0] = *(const float4*)(W_in + c * 4);
        s_wo[tid][0] = W_out[c];
        s_wo[tid][1] = W_out[512 + c];
        s_wo[tid][2] = W_out[1024 + c];
        s_wo[tid][3] = W_out[1536 + c];
        s_bo[tid] = b_out[c];
    }
    __syncthreads();

    // thread owns t = tid*4..+3; block sweeps 64 sequential 16KB c-rows
    float h[4][4] = {}, g[4][4] = {};
    float z2 = 0.f, zb = 0.f;
    const float* zp = z + ((size_t)b * Cv + c0) * Tv + tid * 4;
#pragma unroll 4
    for (int c = 0; c < 64; ++c) {
        const float4 zv = *(const float4*)(zp + (size_t)c * Tv);
        const float4 wi = *(const float4*)&s_wi[c][0];   // wave-uniform broadcast
        const float4 wo = *(const float4*)&s_wo[c][0];
        const float bo = s_bo[c];
        const float zr[4] = {zv.x, zv.y, zv.z, zv.w};
#pragma unroll
        for (int j = 0; j < 4; ++j) {
            h[j][0] = fmaf(zr[j], wi.x, h[j][0]);
            h[j][1] = fmaf(zr[j], wi.y, h[j][1]);
            h[j][2] = fmaf(zr[j], wi.z, h[j][2]);
            h[j][3] = fmaf(zr[j], wi.w, h[j][3]);
            g[j][0] = fmaf(zr[j], wo.x, g[j][0]);
            g[j][1] = fmaf(zr[j], wo.y, g[j][1]);
            g[j][2] = fmaf(zr[j], wo.z, g[j][2]);
            g[j][3] = fmaf(zr[j], wo.w, g[j][3]);
            z2 = fmaf(zr[j], zr[j], z2);
        }
        zb = fmaf((zr[0] + zr[1]) + (zr[2] + zr[3]), bo, zb);
    }

    // partials: [bid][t][e] f32, thread writes 64B contiguous
    float* hp = h_part + ((size_t)bid * Tv + tid * 4) * 4;
    float* gp = g_part + ((size_t)bid * Tv + tid * 4) * 4;
#pragma unroll
    for (int j = 0; j < 4; ++j) {
        f32x4 hv = {h[j][0], h[j][1], h[j][2], h[j][3]};
        f32x4 gv = {g[j][0], g[j][1], g[j][2], g[j][3]};
        __builtin_nontemporal_store(hv, (f32x4*)(hp + j * 4));
        __builtin_nontemporal_store(gv, (f32x4*)(gp + j * 4));
    }

    red[0][tid] = (double)z2;
    red[1][tid] = (double)zb;
    __syncthreads();
    for (int s = 512; s > 0; s >>= 1) {
        if (tid < s) { red[0][tid] += red[0][tid + s]; red[1][tid] += red[1][tid + s]; }
        __syncthreads();
    }
    if (tid == 0) { bs1[bid * 2] = red[0][0]; bs1[bid * 2 + 1] = red[1][0]; }
}

// ---- kB: combine c-split partials -> h,g + BN block stats ----
__global__ __launch_bounds__(256) void fsq_kB(
    const float* __restrict__ h_part, const float* __restrict__ g_part,
    const float* __restrict__ b_in,
    float* __restrict__ h_ws, float* __restrict__ g_ws, double* __restrict__ bs2)
{
    __shared__ double red[8][256];
    const int tid = threadIdx.x;
    const int bid = blockIdx.x;        // 0..511
    const int b = bid >> 4;
    const int t = ((bid & 15) << 8) + tid;
    const int n = (b << 12) + t;

    double hd[4];
    hd[0] = (double)b_in[0]; hd[1] = (double)b_in[1];
    hd[2] = (double)b_in[2]; hd[3] = (double)b_in[3];
    float gg[4] = {0.f, 0.f, 0.f, 0.f};
#pragma unroll
    for (int cs = 0; cs < 8; ++cs) {
        const size_t base = ((size_t)(b * 8 + cs) * Tv + t) * 4;
        const float4 p = *(const float4*)(h_part + base);
        const float4 q = *(const float4*)(g_part + base);
        hd[0] += (double)p.x; hd[1] += (double)p.y;
        hd[2] += (double)p.z; hd[3] += (double)p.w;
        gg[0] += q.x; gg[1] += q.y; gg[2] += q.z; gg[3] += q.w;
    }

    *(float4*)(h_ws + (size_t)n * 4) =
        make_float4((float)hd[0], (float)hd[1], (float)hd[2], (float)hd[3]);
    *(float4*)(g_ws + (size_t)n * 4) = make_float4(gg[0], gg[1], gg[2], gg[3]);

#pragma unroll
    for (int e = 0; e < 4; ++e) {
        red[e][tid] = hd[e];
        red[4 + e][tid] = hd[e] * hd[e];
    }
    __syncthreads();
    for (int s = 128; s > 0; s >>= 1) {
        if (tid < s) {
#pragma unroll
            for (int k = 0; k < 8; ++k) red[k][tid] += red[k][tid + s];
        }
        __syncthreads();
    }
    if (tid == 0) {
#pragma unroll
        for (int k = 0; k < 8; ++k) bs2[bid * 8 + k] = red[k][0];
    }
}

// ---- kS: BN consts + Gram + zero counts ----
__global__ __launch_bounds__(256) void fsq_kS(
    const float* __restrict__ gamma, const float* __restrict__ beta,
    const float* __restrict__ W_out, const float* __restrict__ b_out,
    const double* __restrict__ bs1, const double* __restrict__ bs2,
    double* __restrict__ consts, unsigned* __restrict__ counts)
{
    __shared__ double sbuf[15][256];
    const int tid = threadIdx.x;

    for (int i = tid; i < 1000; i += 256) counts[i] = 0;

    double a[10] = {};
    for (int r = tid; r < 512; r += 256) {
        const double* p = bs2 + (size_t)r * 8;
#pragma unroll
        for (int k = 0; k < 8; ++k) a[k] += p[k];
    }
    a[8] = bs1[tid * 2];          // 256 entries exactly
    a[9] = bs1[tid * 2 + 1];
#pragma unroll
    for (int k = 0; k < 10; ++k) sbuf[k][tid] = a[k];
    __syncthreads();
    for (int s = 128; s > 0; s >>= 1) {
        if (tid < s) {
#pragma unroll
            for (int k = 0; k < 10; ++k) sbuf[k][tid] += sbuf[k][tid + s];
        }
        __syncthreads();
    }
    double tot[10];
    if (tid == 0) {
#pragma unroll
        for (int k = 0; k < 10; ++k) tot[k] = sbuf[k][0];
    }
    __syncthreads();

    double gr[15] = {};
    for (int c = tid; c < 512; c += 256) {
        const double w0 = (double)W_out[c], w1 = (double)W_out[512 + c];
        const double w2 = (double)W_out[1024 + c], w3 = (double)W_out[1536 + c];
        const double bb = (double)b_out[c];
        gr[0] += w0 * w0; gr[1] += w0 * w1; gr[2] += w0 * w2; gr[3] += w0 * w3;
        gr[4] += w1 * w1; gr[5] += w1 * w2; gr[6] += w1 * w3;
        gr[7] += w2 * w2; gr[8] += w2 * w3; gr[9] += w3 * w3;
        gr[10] += w0 * bb; gr[11] += w1 * bb; gr[12] += w2 * bb; gr[13] += w3 * bb;
        gr[14] += bb * bb;
    }
#pragma unroll
    for (int k = 0; k < 15; ++k) sbuf[k][tid] = gr[k];
    __syncthreads();
    for (int s = 128; s > 0; s >>= 1) {
        if (tid < s) {
#pragma unroll
            for (int k = 0; k < 15; ++k) sbuf[k][tid] += sbuf[k][tid + s];
        }
        __syncthreads();
    }
    if (tid == 0) {
        const double Ninv = 1.0 / (double)Nv;
#pragma unroll
        for (int e = 0; e < 4; ++e) {
            const double mu = tot[e] * Ninv;
            const double var = tot[4 + e] * Ninv - mu * mu;   // biased, matches jnp.var
            const double sc = (double)gamma[e] / sqrt(var + 1e-5);
            consts[e] = sc;
            consts[4 + e] = (double)beta[e] - mu * sc;
        }
        consts[8] = tot[8];   // sum z^2
        consts[9] = tot[9];   // sum z.b_out
#pragma unroll
        for (int k = 0; k < 15; ++k) consts[16 + k] = sbuf[k][0];
        constexpr double hl0 = (8.0 - 1.0) * (1.0 - 1e-3) / 2.0;
        consts[31] = tan(0.5 / hl0);
    }
}

// ---- kQ: quantize rows -> codes + histogram + commit partials ----
__global__ __launch_bounds__(256) void fsq_kQ(
    const float* __restrict__ h_ws, const float* __restrict__ g_ws,
    const double* __restrict__ consts, unsigned* __restrict__ counts,
    unsigned short* __restrict__ codes, double* __restrict__ cp)
{
    __shared__ double s_cp[4];
    const int tid = threadIdx.x;
    const int lane = tid & 63;
    const int w = tid >> 6;
    const int n = blockIdx.x * 256 + tid;

    const double sc0 = consts[0], sc1 = consts[1], sc2 = consts[2], sc3 = consts[3];
    const double bi0 = consts[4], bi1 = consts[5], bi2 = consts[6], bi3 = consts[7];
    const double shift0 = consts[31];
    constexpr double hl0 = (8.0 - 1.0) * (1.0 - 1e-3) / 2.0;   // 3.4965
    constexpr double hl1 = (5.0 - 1.0) * (1.0 - 1e-3) / 2.0;   // 1.998

    const float4 hv = *(const float4*)(h_ws + (size_t)n * 4);
    const double hn0 = fma((double)hv.x, sc0, bi0);
    const double hn1 = fma((double)hv.y, sc1, bi1);
    const double hn2 = fma((double)hv.z, sc2, bi2);
    const double hn3 = fma((double)hv.w, sc3, bi3);
    const double r0 = rint(tanh(hn0 + shift0) * hl0 - 0.5);    // [-4,3]
    const double r1 = rint(tanh(hn1) * hl1);                   // [-2,2]
    const double r2 = rint(tanh(hn2) * hl1);
    const double r3 = rint(tanh(hn3) * hl1);
    const double zd0 = r0 * 0.25, zd1 = r1 * 0.5, zd2 = r2 * 0.5, zd3 = r3 * 0.5;

    const int code = ((int)r0 + 4) + ((int)r1 + 2) * 8 + ((int)r2 + 2) * 40
                   + ((int)r3 + 2) * 200;
    codes[n] = (unsigned short)code;
    atomicAdd(&counts[code], 1u);

    const float4 gv = *(const float4*)(g_ws + (size_t)n * 4);
    const double cg = zd0 * (double)gv.x + zd1 * (double)gv.y
                    + zd2 * (double)gv.z + zd3 * (double)gv.w;
    double q = consts[16 + 14]
             + 2.0 * (zd0 * consts[16 + 10] + zd1 * consts[16 + 11]
                    + zd2 * consts[16 + 12] + zd3 * consts[16 + 13])
             + zd0 * zd0 * consts[16 + 0] + zd1 * zd1 * consts[16 + 4]
             + zd2 * zd2 * consts[16 + 7] + zd3 * zd3 * consts[16 + 9]
             + 2.0 * (zd0 * zd1 * consts[16 + 1] + zd0 * zd2 * consts[16 + 2]
                    + zd0 * zd3 * consts[16 + 3] + zd1 * zd2 * consts[16 + 5]
                    + zd1 * zd3 * consts[16 + 6] + zd2 * zd3 * consts[16 + 8]);
    double qsum = q - 2.0 * cg;
#pragma unroll
    for (int m = 1; m < 64; m <<= 1) qsum += __shfl_xor(qsum, m, 64);
    if (lane == 0) s_cp[w] = qsum;
    __syncthreads();
    if (tid == 0) cp[blockIdx.x] = (s_cp[0] + s_cp[1]) + (s_cp[2] + s_cp[3]);
}

// ---- kW: register decode, sequential full-row nt-stores (+finalize in block 0) ----
__global__ __launch_bounds__(1024, 2) void fsq_kW(
    const unsigned short* __restrict__ codes, const float* __restrict__ W_out,
    const float* __restrict__ b_out, const double* __restrict__ cp,
    const double* __restrict__ consts, const unsigned* __restrict__ counts,
    float* __restrict__ out, int out_size)
{
    __shared__ float s_wo[32][4];
    __shared__ float s_bo[32];
    __shared__ double r1[1024], r2[1024];

    const int tid = threadIdx.x;
    const int bid = blockIdx.x;        // 0..511 = b*16 + cslab
    const int b = bid >> 4;
    const int c0 = (bid & 15) << 5;    // 32 c per block

    if (bid == 0) {                    // finalize commit + perplexity
        double c_ = (tid < 512) ? cp[tid] : 0.0;
        double pl = 0.0;
        for (int i = tid; i < 1000; i += 1024) {
            const double em = (double)counts[i] / (double)Nv;
            pl += em * log(em + 1e-10);
        }
        r1[tid] = c_; r2[tid] = pl;
        __syncthreads();
        for (int s = 512; s > 0; s >>= 1) {
            if (tid < s) { r1[tid] += r1[tid + s]; r2[tid] += r2[tid + s]; }
            __syncthreads();
        }
        if (tid == 0) {
            out[out_size - 2] = (float)((consts[8] - 2.0 * consts[9] + r1[0]) / (double)TOTv);
            out[out_size - 1] = (float)exp(-r2[0]);
        }
        __syncthreads();
    }

    if (tid < 32) {
        const int c = c0 + tid;
        s_wo[tid][0] = W_out[c];
        s_wo[tid][1] = W_out[512 + c];
        s_wo[tid][2] = W_out[1024 + c];
        s_wo[tid][3] = W_out[1536 + c];
        s_bo[tid] = b_out[c];
    }
    __syncthreads();

    // decode this thread's 4 consecutive rows into registers
    const ushort4 cd = *(const ushort4*)(codes + (b << 12) + tid * 4);
    float zn[4][4];
#pragma unroll
    for (int j = 0; j < 4; ++j) {
        const int code = (int)((&cd.x)[j]);
        const int x0 = code & 7;
        const int c1 = code >> 3;
        const int x1 = c1 % 5;
        const int c2 = c1 / 5;
        const int x2 = c2 % 5;
        const int x3 = c2 / 5;
        zn[j][0] = (float)(x0 - 4) * 0.25f;
        zn[j][1] = (float)(x1 - 2) * 0.5f;
        zn[j][2] = (float)(x2 - 2) * 0.5f;
        zn[j][3] = (float)(x3 - 2) * 0.5f;
    }

    // sweep 32 c-rows; per c the block stores one full 16KB row (float4/lane)
    float* op = out + ((size_t)b * Cv + c0) * Tv + tid * 4;
#pragma unroll 4
    for (int ci = 0; ci < 32; ++ci) {
        const float4 wo = *(const float4*)&s_wo[ci][0];   // wave-uniform broadcast
        const float bo = s_bo[ci];
        f32x4 o;
#pragma unroll
        for (int j = 0; j < 4; ++j)
            o[j] = fmaf(zn[j][0], wo.x, fmaf(zn[j][1], wo.y,
                   fmaf(zn[j][2], wo.z, fmaf(zn[j][3], wo.w, bo))));
        __builtin_nontemporal_store(o, (f32x4*)(op + (size_t)ci * Tv));
    }
}

extern "C" void kernel_launch(void* const* d_in, const int* in_sizes, int n_in,
                              void* d_out, int out_size, void* d_ws, size_t ws_size,
                              hipStream_t stream) {
    const float* z     = (const float*)d_in[0];
    const float* W_in  = (const float*)d_in[1];
    const float* b_in  = (const float*)d_in[2];
    const float* gamma = (const float*)d_in[3];
    const float* beta  = (const float*)d_in[4];
    const float* W_out = (const float*)d_in[5];
    const float* b_out = (const float*)d_in[6];
    float* out = (float*)d_out;

    char* ws = (char*)d_ws;
    float*          h_part = (float*)(ws + OFF_HP);
    float*          g_part = (float*)(ws + OFF_GP);
    float*          h_ws   = (float*)(ws + OFF_H);
    float*          g_ws   = (float*)(ws + OFF_G);
    double*         bs1    = (double*)(ws + OFF_B1);
    double*         bs2    = (double*)(ws + OFF_B2);
    double*         consts = (double*)(ws + OFF_CN);
    double*         cp     = (double*)(ws + OFF_CP);
    unsigned*       counts = (unsigned*)(ws + OFF_CT);
    unsigned short* codes  = (unsigned short*)(ws + OFF_CD);

    fsq_kA<<<NBA, 1024, 0, stream>>>(z, W_in, W_out, b_out, h_part, g_part, bs1);
    fsq_kB<<<512, 256, 0, stream>>>(h_part, g_part, b_in, h_ws, g_ws, bs2);
    fsq_kS<<<1, 256, 0, stream>>>(gamma, beta, W_out, b_out, bs1, bs2, consts, counts);
    fsq_kQ<<<512, 256, 0, stream>>>(h_ws, g_ws, consts, counts, codes, cp);
    fsq_kW<<<512, 1024, 0, stream>>>(codes, W_out, b_out, cp, consts, counts, out, out_size);
}